// Round 18
// baseline (195.786 us; speedup 1.0000x reference)
//
#include <hip/hip_runtime.h>
#include <hip/hip_bf16.h>
#include <cstddef>

typedef __bf16 bf16x8 __attribute__((ext_vector_type(8)));
typedef float f32x4 __attribute__((ext_vector_type(4)));

// ---------------- fused prep kernel (unchanged) ----------------
__global__ void prep_all_kernel(const float* __restrict__ x, __hip_bfloat16* __restrict__ act0,
                                const float* __restrict__ w1, __hip_bfloat16* __restrict__ o1,
                                const float* __restrict__ w2, __hip_bfloat16* __restrict__ o2,
                                const float* __restrict__ w3, __hip_bfloat16* __restrict__ o3,
                                const float* __restrict__ w4, __hip_bfloat16* __restrict__ o4,
                                const float* __restrict__ w5, __hip_bfloat16* __restrict__ o5,
                                const float* __restrict__ wf, __hip_bfloat16* __restrict__ of,
                                const float* __restrict__ style,
                                const float* __restrict__ fw1, const float* __restrict__ fb1,
                                const float* __restrict__ fw2, const float* __restrict__ fb2,
                                const float* __restrict__ fw3, const float* __restrict__ fb3,
                                const float* __restrict__ fw4, const float* __restrict__ fb4,
                                const float* __restrict__ fw5, const float* __restrict__ fb5,
                                float* __restrict__ S) {
    const int blk = blockIdx.x;
    if (blk < 1024) {
        int t = blk * 256 + threadIdx.x;          // 262144 total
        int c = t & 511; int rest = t >> 9;
        int w = rest & 7; rest >>= 3; int h = rest & 7; int b = rest >> 3;
        act0[t] = __float2bfloat16(x[((b * 512 + c) * 8 + h) * 8 + w]);
    } else if (blk < 12324) {
        int t = (blk - 1024) * 256 + threadIdx.x;   // < 2892800
        if (t < 2752512) {
            // stages 1-3 parity-summed fragment layout
            const float* w; __hip_bfloat16* o; int CI, lgCICH, lgCO16;
            if      (t < 2097152) { w = w1; o = o1; CI = 512; lgCICH = 3; lgCO16 = 4; }
            else if (t < 2621440) { t -= 2097152; w = w2; o = o2; CI = 256; lgCICH = 2; lgCO16 = 3; }
            else                  { t -= 2621440; w = w3; o = o3; CI = 128; lgCICH = 1; lgCO16 = 2; }
            int j    = t & 7;
            int ln   = (t >> 3) & 63;
            int ch   = (t >> 9) & 1;
            int cich = (t >> 10) & ((1 << lgCICH) - 1);
            int co16 = (t >> (10 + lgCICH)) & ((1 << lgCO16) - 1);
            int tap  = (t >> (10 + lgCICH + lgCO16)) & 3;
            int cls  = (t >> (12 + lgCICH + lgCO16)) & 3;
            int co = co16 * 16 + (ln & 15);
            int ci = cich * 64 + ch * 32 + (ln >> 4) * 8 + j;
            int py = cls >> 1, px = cls & 1;
            int i = tap >> 1, jj = tap & 1;
            int r0 = i * (1 + py), rc = py ? (2 - i) : (1 + i);
            int c0 = jj * (1 + px), cc = px ? (2 - jj) : (1 + jj);
            const float* wb = w + ((size_t)co * CI + ci) * 9;
            float s = 0.f;
            for (int rr = 0; rr < rc; ++rr)
                for (int c2 = 0; c2 < cc; ++c2)
                    s += wb[(r0 + rr) * 3 + (c0 + c2)];
            o[t] = __float2bfloat16(s);
        } else if (t < 2883584) {
            // stages 4/5 parity-packed
            int u = t - 2752512;
            const float* w; __hip_bfloat16* o;
            if (u < 65536) { w = w4; o = o4; }
            else           { u -= 65536; w = w5; o = o5; }
            int j   = u & 7;
            int ln  = (u >> 3) & 63;
            int ch  = (u >> 9) & 1;
            int nt  = (u >> 10) & 3;
            int tp  = (u >> 12) & 3;
            int cls = (u >> 14) & 3;
            int py = cls >> 1, px = cls & 1;
            int i = tp >> 1, jj = tp & 1;
            int co = nt * 16 + (ln & 15);
            int ci = ch * 32 + (ln >> 4) * 8 + j;
            int r0 = i * (1 + py), rc = py ? (2 - i) : (1 + i);
            int c0 = jj * (1 + px), cc = px ? (2 - jj) : (1 + jj);
            const float* wb = w + ((size_t)co * 64 + ci) * 9;
            float s = 0.f;
            for (int rr = 0; rr < rc; ++rr)
                for (int c2 = 0; c2 < cc; ++c2)
                    s += wb[(r0 + rr) * 3 + (c0 + c2)];
            o[u] = __float2bfloat16(s);
        } else if (t < 2892800) {
            // packed final-conv 16x16x32 layout (9216 elems), co padded 3->16
            int u = t - 2883584;
            int j  = u & 7;
            int ln = (u >> 3) & 63;
            int ch = (u >> 9) & 1;
            int tap = u >> 10;
            int rr = ln & 15, qq = ln >> 4;
            int ci = ch * 32 + qq * 8 + j;
            float v = (rr < 3) ? wf[((size_t)rr * 64 + ci) * 9 + tap] : 0.f;
            of[u] = __float2bfloat16(v);
        }
    } else {
        int wvid = (blk - 12324) * 4 + (threadIdx.x >> 6);
        int lane = threadIdx.x & 63;
        const float* fw; const float* fb; int lg, sOff, local;
        if      (wvid < 2048) { fw = fw1; fb = fb1; lg = 8; sOff = 0;    local = wvid; }
        else if (wvid < 3072) { fw = fw2; fb = fb2; lg = 7; sOff = 2048; local = wvid - 2048; }
        else if (wvid < 3584) { fw = fw3; fb = fb3; lg = 6; sOff = 3072; local = wvid - 3072; }
        else if (wvid < 4096) { fw = fw4; fb = fb4; lg = 6; sOff = 3584; local = wvid - 3584; }
        else                  { fw = fw5; fb = fb5; lg = 6; sOff = 4096; local = wvid - 4096; }
        int b = local >> lg, o = local & ((1 << lg) - 1);
        const float* sb = style + b * 512;
        const float* fwo = fw + (size_t)o * 512;
        float p = 0.f;
        #pragma unroll
        for (int k = lane; k < 512; k += 64) p += sb[k] * fwo[k];
        #pragma unroll
        for (int off = 32; off > 0; off >>= 1) p += __shfl_down(p, off);
        if (lane == 0) S[sOff + local] = p + fb[o];
    }
}

// ---------------- stages 1-3: K-full parity-decomposed conv (unchanged) --------------
template <int HS, int CI, int CO, int NT>
__launch_bounds__(256)
__global__ void conv_sfull_kernel(const __hip_bfloat16* __restrict__ actIn,
                                  const __hip_bfloat16* __restrict__ wpk,
                                  const float* __restrict__ S,
                                  __hip_bfloat16* __restrict__ actOut) {
    constexpr int WS = HS, HO = HS * 2;
    constexpr int CICH = CI / 64, CO16 = CO / 16;
    constexpr int PW = HO / 8, PPI = PW * PW;

    const int tid = threadIdx.x;
    const int lane = tid & 63, wv = tid >> 6;        // wv = parity class
    const int r = lane & 15, q = lane >> 4;
    const int rr2 = r >> 2, cc2 = r & 3;
    const int lane8 = lane * 8;
    const int py = wv >> 1, px = wv & 1;

    const int b = blockIdx.x / PPI;
    const int prest = blockIdx.x - b * PPI;
    const int ph = prest / PW, pwi = prest - ph * PW;
    const int oh0 = ph * 8, ow0 = pwi * 8;
    const int sh0 = oh0 >> 1, sw0 = ow0 >> 1;
    const int co16base = blockIdx.y * NT;
    const int n0 = co16base * 16;

    __shared__ alignas(16) __hip_bfloat16 Tile[36 * 72];   // 6x6 px x 64 ci

    f32x4 acc[NT];
    #pragma unroll
    for (int j = 0; j < NT; ++j) acc[j] = f32x4{0.f, 0.f, 0.f, 0.f};

    bf16x8 bA[NT][2], bB[NT][2];

    #pragma unroll 1
    for (int cich = 0; cich < CICH; ++cich) {
        if (cich) __syncthreads();                   // all waves done with previous Tile
        for (int i = tid; i < 288; i += 256) {
            int pix = i >> 3, koct = i & 7;
            int tr = pix / 6, tc2 = pix - tr * 6;
            int su = sh0 - 1 + tr, sv = sw0 - 1 + tc2;
            uint4 v = {0, 0, 0, 0};
            if (su >= 0 && su < HS && sv >= 0 && sv < WS)
                v = *(const uint4*)(actIn +
                    ((size_t)((b * HS + su) * WS + sv) * CI + cich * 64 + koct * 8));
            *(uint4*)&Tile[pix * 72 + koct * 8] = v;
        }
        __syncthreads();

        auto loadB = [&](bf16x8 (&dst)[NT][2], int tp) {
            #pragma unroll
            for (int nt = 0; nt < NT; ++nt)
                #pragma unroll
                for (int ch = 0; ch < 2; ++ch)
                    dst[nt][ch] = *(const bf16x8*)(wpk +
                        ((size_t)((((wv * 4 + tp) * CO16 + co16base + nt) * CICH + cich) * 2 + ch) << 9) + lane8);
        };

        auto compute = [&](int tp, bf16x8 (&bfr)[NT][2]) {
            const int i = tp >> 1, j = tp & 1;
            const int apix = (rr2 + i + py) * 6 + (cc2 + j + px);
            #pragma unroll
            for (int ch = 0; ch < 2; ++ch) {
                bf16x8 af = *(const bf16x8*)&Tile[apix * 72 + ch * 32 + q * 8];
                #pragma unroll
                for (int nt = 0; nt < NT; ++nt)
                    acc[nt] = __builtin_amdgcn_mfma_f32_16x16x32_bf16(
                        af, bfr[nt][ch], acc[nt], 0, 0, 0);
            }
        };

        loadB(bA, 0);
        loadB(bB, 1);
        compute(0, bA);
        loadB(bA, 2);
        compute(1, bB);
        loadB(bB, 3);
        compute(2, bA);
        compute(3, bB);
    }

    float sv_[NT];
    #pragma unroll
    for (int nt = 0; nt < NT; ++nt) sv_[nt] = S[b * CO + n0 + nt * 16 + r];
    #pragma unroll
    for (int t2 = 0; t2 < 4; ++t2) {
        const int m = q * 4 + t2;
        const int row = oh0 + 2 * (m >> 2) + py;
        const int col = ow0 + 2 * (m & 3) + px;
        const size_t obase = ((size_t)(b * HO + row) * HO + col) * CO + n0;
        #pragma unroll
        for (int nt = 0; nt < NT; ++nt)
            actOut[obase + nt * 16 + r] =
                __float2bfloat16(fmaxf(acc[nt][t2] * sv_[nt], 0.f));
    }
}

// ---------------- stage 4: parity-decomposed 2x2 taps, CO-split (unchanged) ----------
template <int HS, int WS>
__launch_bounds__(256)
__global__ void conv_patch_kernel(const __hip_bfloat16* __restrict__ actIn,
                                  const __hip_bfloat16* __restrict__ wpk,
                                  const float* __restrict__ S,
                                  __hip_bfloat16* __restrict__ actOut) {
    constexpr int HO = HS * 2, WO = WS * 2;

    const int tid = threadIdx.x;
    const int lane = tid & 63, wv = tid >> 6;        // wv = parity class
    const int r = lane & 15, q = lane >> 4;
    const int rs = r >> 3, sc = r & 7;
    const int lane8 = lane * 8;
    const int py = wv >> 1, px = wv & 1;

    const int pw = WO / 16, ppb = (HO / 16) * pw;
    const int b = blockIdx.x / ppb;
    const int prest = blockIdx.x - b * ppb;
    const int ph = prest / pw, pwi = prest - ph * pw;
    const int oh0 = ph * 16, ow0 = pwi * 16;
    const int sh0 = oh0 >> 1, sw0 = ow0 >> 1;
    const int ntBase = blockIdx.y * 2;               // co half: 2 of 4 co16-groups

    __shared__ alignas(16) __hip_bfloat16 Tile[100 * 72];

    f32x4 acc[4][2];
    #pragma unroll
    for (int i = 0; i < 4; ++i)
        #pragma unroll
        for (int j = 0; j < 2; ++j) acc[i][j] = f32x4{0.f, 0.f, 0.f, 0.f};

    for (int i = tid; i < 800; i += 256) {
        int pix = i >> 3, koct = i & 7;
        int tr = pix / 10, tc2 = pix - tr * 10;
        int su = sh0 - 1 + tr, sv = sw0 - 1 + tc2;
        uint4 v = {0, 0, 0, 0};
        if (su >= 0 && su < HS && sv >= 0 && sv < WS)
            v = *(const uint4*)(actIn + ((size_t)((b * HS + su) * WS + sv) * 64 + koct * 8));
        *(uint4*)&Tile[pix * 72 + koct * 8] = v;
    }
    __syncthreads();

    const __hip_bfloat16* wcls = wpk + ((size_t)wv << 14);

    bf16x8 bA[2][2], bB[2][2];

    auto loadB = [&](bf16x8 (&dst)[2][2], int tp) {
        #pragma unroll
        for (int nt = 0; nt < 2; ++nt)
            #pragma unroll
            for (int ch = 0; ch < 2; ++ch)
                dst[nt][ch] = *(const bf16x8*)(wcls + (tp << 12) + (((ntBase + nt) * 2 + ch) << 9) + lane8);
    };

    auto compute = [&](int tp, bf16x8 (&bfr)[2][2]) {
        const int i = tp >> 1, j = tp & 1;
        const int ro = i + py, co2 = j + px;
        int apix[4];
        #pragma unroll
        for (int mt = 0; mt < 4; ++mt)
            apix[mt] = (2 * mt + rs + ro) * 10 + (sc + co2);
        #pragma unroll
        for (int ch = 0; ch < 2; ++ch) {
            bf16x8 af[4];
            #pragma unroll
            for (int mt = 0; mt < 4; ++mt)
                af[mt] = *(const bf16x8*)&Tile[apix[mt] * 72 + ch * 32 + q * 8];
            #pragma unroll
            for (int mt = 0; mt < 4; ++mt)
                #pragma unroll
                for (int nt = 0; nt < 2; ++nt)
                    acc[mt][nt] = __builtin_amdgcn_mfma_f32_16x16x32_bf16(
                        af[mt], bfr[nt][ch], acc[mt][nt], 0, 0, 0);
        }
    };

    loadB(bA, 0);
    loadB(bB, 1);
    compute(0, bA);
    loadB(bA, 2);
    compute(1, bB);
    loadB(bB, 3);
    compute(2, bA);
    compute(3, bB);

    float sv_[2];
    #pragma unroll
    for (int nt = 0; nt < 2; ++nt) sv_[nt] = S[b * 64 + (ntBase + nt) * 16 + r];
    #pragma unroll
    for (int mt = 0; mt < 4; ++mt) {
        #pragma unroll
        for (int t2 = 0; t2 < 4; ++t2) {
            const int m = q * 4 + t2;
            const int row = oh0 + 4 * mt + 2 * (m >> 3) + py;
            const int col = ow0 + 2 * (m & 7) + px;
            const size_t obase = ((size_t)(b * HO + row) * WO + col) * 64;
            #pragma unroll
            for (int nt = 0; nt < 2; ++nt)
                actOut[obase + (ntBase + nt) * 16 + r] =
                    __float2bfloat16(fmaxf(acc[mt][nt][t2] * sv_[nt], 0.f));
        }
    }
}

// ---------------- fused stage 5 + final conv: 8x16 tiles, 256 threads ----------------
// Halved tile vs R13: 4096 blocks x 4 waves, LDS 25.9 KB (act4 6x10 tile aliased into
// the act5 10x18 patch) -> ~2x resident blocks + 2x block count for latency hiding.
// Per class: act5 grid 5x9 = 45 px (3 m-tiles, masked at 45). Same weights/rounding.
__launch_bounds__(256)
__global__ void conv_s5f_kernel(const __hip_bfloat16* __restrict__ actIn,  // [8][128][128][64]
                                const __hip_bfloat16* __restrict__ wpk5,   // wt5 parity-packed
                                const __hip_bfloat16* __restrict__ wpkF,   // [9][2][64][8]
                                const float* __restrict__ S,
                                const float* __restrict__ bias,
                                float* __restrict__ out) {                 // [8][3][256][256]
    constexpr int HS = 128, WS = 128;

    const int tid = threadIdx.x;
    const int lane = tid & 63, wv = tid >> 6;        // 4 waves = 4 parity classes
    const int r = lane & 15, q = lane >> 4;
    const int lane8 = lane * 8;
    const int py = wv >> 1, px = wv & 1;

    const int bid = blockIdx.x;                      // 8 * 32 * 16 = 4096
    const int b = bid >> 9;
    const int rest = bid & 511;
    const int oh0 = (rest >> 4) * 8, ow0 = (rest & 15) * 16;   // final tile origin (8x16)
    const int sh0 = oh0 >> 1, sw0 = ow0 >> 1;

    __shared__ alignas(16) __hip_bfloat16 Lds[10 * 18 * 72];   // act5 patch; act4 aliased
    __hip_bfloat16* TileA = Lds;                               // first 60*72 elems

    // ---- stage act4 tile (6 rows x 10 cols x 64ci, stride 72) ----
    for (int i = tid; i < 480; i += 256) {
        int pix = i >> 3, koct = i & 7;
        int tr = pix / 10, tc2 = pix - tr * 10;
        int su = sh0 - 1 + tr, sv = sw0 - 1 + tc2;
        uint4 v = {0, 0, 0, 0};
        if (su >= 0 && su < HS && sv >= 0 && sv < WS)
            v = *(const uint4*)(actIn + ((size_t)((b * HS + su) * WS + sv) * 64 + koct * 8));
        *(uint4*)&TileA[pix * 72 + koct * 8] = v;
    }
    __syncthreads();

    // ---- stage-5 compute: per class 5x9 px grid (45 px), 3 m-tiles ----
    f32x4 acc[3][4];                                 // [mt][nt]
    #pragma unroll
    for (int i = 0; i < 3; ++i)
        #pragma unroll
        for (int j = 0; j < 4; ++j) acc[i][j] = f32x4{0.f, 0.f, 0.f, 0.f};

    int jrA[3], jcA[3];                              // class-grid coords (clamped)
    #pragma unroll
    for (int mt = 0; mt < 3; ++mt) {
        int pm = mt * 16 + r;
        pm = pm > 44 ? 44 : pm;
        jrA[mt] = (pm * 57) >> 9;                    // pm / 9 (exact for pm<=95)
        jcA[mt] = pm - jrA[mt] * 9;
    }

    const __hip_bfloat16* wcls = wpk5 + ((size_t)wv << 14);

    bf16x8 bA[4][2], bB[4][2];                       // [nt][ch]

    auto loadB = [&](bf16x8 (&dst)[4][2], int tp) {
        #pragma unroll
        for (int nt = 0; nt < 4; ++nt)
            #pragma unroll
            for (int ch = 0; ch < 2; ++ch)
                dst[nt][ch] = *(const bf16x8*)(wcls + (tp << 12) + ((nt * 2 + ch) << 9) + lane8);
    };

    auto compute = [&](int tp, bf16x8 (&bfr)[4][2]) {
        const int i = tp >> 1, j = tp & 1;
        int apix[3];
        #pragma unroll
        for (int mt = 0; mt < 3; ++mt)
            apix[mt] = (jrA[mt] + i) * 10 + (jcA[mt] + j);
        #pragma unroll
        for (int ch = 0; ch < 2; ++ch) {
            bf16x8 af[3];
            #pragma unroll
            for (int mt = 0; mt < 3; ++mt)
                af[mt] = *(const bf16x8*)&TileA[apix[mt] * 72 + ch * 32 + q * 8];
            #pragma unroll
            for (int mt = 0; mt < 3; ++mt)
                #pragma unroll
                for (int nt = 0; nt < 4; ++nt)
                    acc[mt][nt] = __builtin_amdgcn_mfma_f32_16x16x32_bf16(
                        af[mt], bfr[nt][ch], acc[mt][nt], 0, 0, 0);
        }
    };

    loadB(bA, 0);
    loadB(bB, 1);
    compute(0, bA);
    loadB(bA, 2);
    compute(1, bB);
    loadB(bB, 3);
    compute(2, bA);
    compute(3, bB);

    float sv_[4];
    #pragma unroll
    for (int nt = 0; nt < 4; ++nt) sv_[nt] = S[b * 64 + nt * 16 + r];

    __syncthreads();                                 // all TileA reads done

    // ---- write act5 patch to LDS (classes partition the 10x18 grid;
    //      out-of-image px written as 0 = conv zero-padding) ----
    #pragma unroll
    for (int mt = 0; mt < 3; ++mt) {
        #pragma unroll
        for (int t2 = 0; t2 < 4; ++t2) {
            const int m = mt * 16 + q * 4 + t2;
            if (m < 45) {
                const int jr = (m * 57) >> 9;
                const int jc = m - jr * 9;
                const int p  = py ? (oh0 - 1 + 2 * jr) : (oh0 + 2 * jr);
                const int pc = px ? (ow0 - 1 + 2 * jc) : (ow0 + 2 * jc);
                const bool valid = (p >= 0) && (p < 256) && (pc >= 0) && (pc < 256);
                const int dpx = (2 * jr + 1 - py) * 18 + (2 * jc + 1 - px);
                #pragma unroll
                for (int nt = 0; nt < 4; ++nt) {
                    float v = valid ? fmaxf(acc[mt][nt][t2] * sv_[nt], 0.f) : 0.f;
                    Lds[dpx * 72 + nt * 16 + r] = __float2bfloat16(v);
                }
            }
        }
    }
    __syncthreads();

    // ---- final conv from LDS: 4 waves x 2 rows x 16 cols ----
    f32x4 acc2[2];
    acc2[0] = f32x4{0.f, 0.f, 0.f, 0.f};
    acc2[1] = f32x4{0.f, 0.f, 0.f, 0.f};

    #pragma unroll 1
    for (int tap = 0; tap < 9; ++tap) {
        const int dyv = tap / 3;
        const int dxv = tap - dyv * 3;
        const int tc = r + dxv;
        int apix[2];
        #pragma unroll
        for (int mt = 0; mt < 2; ++mt)
            apix[mt] = (wv * 2 + mt + dyv) * 18 + tc;
        #pragma unroll
        for (int ch = 0; ch < 2; ++ch) {
            bf16x8 bfr = *(const bf16x8*)(wpkF + ((tap * 2 + ch) << 9) + lane8);
            #pragma unroll
            for (int mt = 0; mt < 2; ++mt) {
                bf16x8 af = *(const bf16x8*)&Lds[apix[mt] * 72 + ch * 32 + q * 8];
                acc2[mt] = __builtin_amdgcn_mfma_f32_16x16x32_bf16(af, bfr, acc2[mt], 0, 0, 0);
            }
        }
    }

    if (r < 3) {
        const float bs = bias[r];
        #pragma unroll
        for (int mt = 0; mt < 2; ++mt) {
            const int prow = oh0 + wv * 2 + mt;
            #pragma unroll
            for (int t2 = 0; t2 < 4; ++t2)
                out[((size_t)(b * 3 + r) << 16) + prow * 256 + ow0 + q * 4 + t2] =
                    acc2[mt][t2] + bs;
        }
    }
}

// ---------------- launch ----------------
extern "C" void kernel_launch(void* const* d_in, const int* in_sizes, int n_in,
                              void* d_out, int out_size, void* d_ws, size_t ws_size,
                              hipStream_t stream) {
    const float* x    = (const float*)d_in[0];
    const float* sty  = (const float*)d_in[1];
    const float* w1   = (const float*)d_in[2];
    const float* fw1  = (const float*)d_in[3];
    const float* fb1  = (const float*)d_in[4];
    const float* w2   = (const float*)d_in[5];
    const float* fw2  = (const float*)d_in[6];
    const float* fb2  = (const float*)d_in[7];
    const float* w3   = (const float*)d_in[8];
    const float* fw3  = (const float*)d_in[9];
    const float* fb3  = (const float*)d_in[10];
    const float* w4   = (const float*)d_in[11];
    const float* fw4  = (const float*)d_in[12];
    const float* fb4  = (const float*)d_in[13];
    const float* w5   = (const float*)d_in[14];
    const float* fw5  = (const float*)d_in[15];
    const float* fb5  = (const float*)d_in[16];
    const float* wf   = (const float*)d_in[17];
    const float* bf   = (const float*)d_in[18];
    float* out = (float*)d_out;

    char* ws = (char*)d_ws;
    size_t off = 0;
    auto alloc = [&](size_t bytes) {
        char* p = ws + off;
        off += (bytes + 255) & ~(size_t)255;
        return p;
    };
    float* S1 = (float*)alloc(8 * 256 * 4);
    float* S2 = (float*)alloc(8 * 128 * 4);
    float* S3 = (float*)alloc(8 * 64 * 4);
    float* S4 = (float*)alloc(8 * 64 * 4);
    float* S5 = (float*)alloc(8 * 64 * 4);
    __hip_bfloat16* act0 = (__hip_bfloat16*)alloc((size_t)262144 * 2);   // 8x8x8x512
    __hip_bfloat16* act1 = (__hip_bfloat16*)alloc((size_t)524288 * 2);   // 8x16x16x256
    __hip_bfloat16* act2 = (__hip_bfloat16*)alloc((size_t)1048576 * 2);  // 8x32x32x128
    __hip_bfloat16* act3 = (__hip_bfloat16*)alloc((size_t)2097152 * 2);  // 8x64x64x64
    __hip_bfloat16* act4 = (__hip_bfloat16*)alloc((size_t)8388608 * 2);  // 8x128x128x64
    __hip_bfloat16* wt1  = (__hip_bfloat16*)alloc((size_t)2097152 * 2);  // parity-packed
    __hip_bfloat16* wt2  = (__hip_bfloat16*)alloc((size_t)524288 * 2);   // parity-packed
    __hip_bfloat16* wt3  = (__hip_bfloat16*)alloc((size_t)131072 * 2);   // parity-packed
    __hip_bfloat16* wt4  = (__hip_bfloat16*)alloc((size_t)65536 * 2);    // parity-packed
    __hip_bfloat16* wt5  = (__hip_bfloat16*)alloc((size_t)65536 * 2);    // parity-packed
    __hip_bfloat16* wtF  = (__hip_bfloat16*)alloc((size_t)9 * 16 * 64 * 2); // packed 16x16
    if (off > ws_size) return;

    // fused prep: convert_x [0,1024) | weights [1024,12324) | style [12324,13476)
    prep_all_kernel<<<13476, 256, 0, stream>>>(x, act0,
                                               w1, wt1, w2, wt2, w3, wt3,
                                               w4, wt4, w5, wt5, wf, wtF,
                                               sty, fw1, fb1, fw2, fb2, fw3, fb3,
                                               fw4, fb4, fw5, fb5, S1);

    // stages 1-3: K-full parity-decomposed; s2/s3 CO-split for 2x block count
    conv_sfull_kernel<8, 512, 256, 1><<<dim3(32, 16), 256, 0, stream>>>(act0, wt1, S1, act1);
    conv_sfull_kernel<16, 256, 128, 1><<<dim3(128, 8), 256, 0, stream>>>(act1, wt2, S2, act2);
    conv_sfull_kernel<32, 128, 64, 2><<<dim3(512, 2), 256, 0, stream>>>(act2, wt3, S3, act3);

    // stage 4: parity-decomposed 2x2-tap fused conv, CO-split (1024 blocks)
    conv_patch_kernel<64, 64><<<dim3(512, 2), 256, 0, stream>>>(act3, wt4, S4, act4);

    // stage 5 + final conv fused: 8x16 tiles, 4096 blocks x 256 threads
    conv_s5f_kernel<<<4096, 256, 0, stream>>>(act4, wt5, wtF, S5, bf, out);
}

// Round 19
// 189.281 us; speedup vs baseline: 1.0344x; 1.0344x over previous
//
#include <hip/hip_runtime.h>
#include <hip/hip_bf16.h>
#include <cstddef>

typedef __bf16 bf16x8 __attribute__((ext_vector_type(8)));
typedef float f32x4 __attribute__((ext_vector_type(4)));

// ---------------- fused prep kernel ----------------
__global__ void prep_all_kernel(const float* __restrict__ x, __hip_bfloat16* __restrict__ act0,
                                const float* __restrict__ w1, __hip_bfloat16* __restrict__ o1,
                                const float* __restrict__ w2, __hip_bfloat16* __restrict__ o2,
                                const float* __restrict__ w3, __hip_bfloat16* __restrict__ o3,
                                const float* __restrict__ w4, __hip_bfloat16* __restrict__ o4,
                                const float* __restrict__ w5, __hip_bfloat16* __restrict__ o5,
                                const float* __restrict__ wf, __hip_bfloat16* __restrict__ of,
                                const float* __restrict__ style,
                                const float* __restrict__ fw1, const float* __restrict__ fb1,
                                const float* __restrict__ fw2, const float* __restrict__ fb2,
                                const float* __restrict__ fw3, const float* __restrict__ fb3,
                                const float* __restrict__ fw4, const float* __restrict__ fb4,
                                const float* __restrict__ fw5, const float* __restrict__ fb5,
                                float* __restrict__ S) {
    const int blk = blockIdx.x;
    if (blk < 1024) {
        int t = blk * 256 + threadIdx.x;          // 262144 total
        int c = t & 511; int rest = t >> 9;
        int w = rest & 7; rest >>= 3; int h = rest & 7; int b = rest >> 3;
        act0[t] = __float2bfloat16(x[((b * 512 + c) * 8 + h) * 8 + w]);
    } else if (blk < 12324) {
        int t = (blk - 1024) * 256 + threadIdx.x;   // < 2892800
        if (t < 2752512) {
            // stages 1-3 parity-summed fragment layout
            const float* w; __hip_bfloat16* o; int CI, lgCICH, lgCO16;
            if      (t < 2097152) { w = w1; o = o1; CI = 512; lgCICH = 3; lgCO16 = 4; }
            else if (t < 2621440) { t -= 2097152; w = w2; o = o2; CI = 256; lgCICH = 2; lgCO16 = 3; }
            else                  { t -= 2621440; w = w3; o = o3; CI = 128; lgCICH = 1; lgCO16 = 2; }
            int j    = t & 7;
            int ln   = (t >> 3) & 63;
            int ch   = (t >> 9) & 1;
            int cich = (t >> 10) & ((1 << lgCICH) - 1);
            int co16 = (t >> (10 + lgCICH)) & ((1 << lgCO16) - 1);
            int tap  = (t >> (10 + lgCICH + lgCO16)) & 3;
            int cls  = (t >> (12 + lgCICH + lgCO16)) & 3;
            int co = co16 * 16 + (ln & 15);
            int ci = cich * 64 + ch * 32 + (ln >> 4) * 8 + j;
            int py = cls >> 1, px = cls & 1;
            int i = tap >> 1, jj = tap & 1;
            int r0 = i * (1 + py), rc = py ? (2 - i) : (1 + i);
            int c0 = jj * (1 + px), cc = px ? (2 - jj) : (1 + jj);
            const float* wb = w + ((size_t)co * CI + ci) * 9;
            float s = 0.f;
            for (int rr = 0; rr < rc; ++rr)
                for (int c2 = 0; c2 < cc; ++c2)
                    s += wb[(r0 + rr) * 3 + (c0 + c2)];
            o[t] = __float2bfloat16(s);
        } else if (t < 2883584) {
            // stages 4/5 parity-packed
            int u = t - 2752512;
            const float* w; __hip_bfloat16* o;
            if (u < 65536) { w = w4; o = o4; }
            else           { u -= 65536; w = w5; o = o5; }
            int j   = u & 7;
            int ln  = (u >> 3) & 63;
            int ch  = (u >> 9) & 1;
            int nt  = (u >> 10) & 3;
            int tp  = (u >> 12) & 3;
            int cls = (u >> 14) & 3;
            int py = cls >> 1, px = cls & 1;
            int i = tp >> 1, jj = tp & 1;
            int co = nt * 16 + (ln & 15);
            int ci = ch * 32 + (ln >> 4) * 8 + j;
            int r0 = i * (1 + py), rc = py ? (2 - i) : (1 + i);
            int c0 = jj * (1 + px), cc = px ? (2 - jj) : (1 + jj);
            const float* wb = w + ((size_t)co * 64 + ci) * 9;
            float s = 0.f;
            for (int rr = 0; rr < rc; ++rr)
                for (int c2 = 0; c2 < cc; ++c2)
                    s += wb[(r0 + rr) * 3 + (c0 + c2)];
            o[u] = __float2bfloat16(s);
        } else if (t < 2892800) {
            // packed final-conv 16x16x32 layout (9216 elems), co padded 3->16
            int u = t - 2883584;
            int j  = u & 7;
            int ln = (u >> 3) & 63;
            int ch = (u >> 9) & 1;
            int tap = u >> 10;
            int rr = ln & 15, qq = ln >> 4;
            int ci = ch * 32 + qq * 8 + j;
            float v = (rr < 3) ? wf[((size_t)rr * 64 + ci) * 9 + tap] : 0.f;
            of[u] = __float2bfloat16(v);
        }
    } else {
        int wvid = (blk - 12324) * 4 + (threadIdx.x >> 6);
        int lane = threadIdx.x & 63;
        const float* fw; const float* fb; int lg, sOff, local;
        if      (wvid < 2048) { fw = fw1; fb = fb1; lg = 8; sOff = 0;    local = wvid; }
        else if (wvid < 3072) { fw = fw2; fb = fb2; lg = 7; sOff = 2048; local = wvid - 2048; }
        else if (wvid < 3584) { fw = fw3; fb = fb3; lg = 6; sOff = 3072; local = wvid - 3072; }
        else if (wvid < 4096) { fw = fw4; fb = fb4; lg = 6; sOff = 3584; local = wvid - 3584; }
        else                  { fw = fw5; fb = fb5; lg = 6; sOff = 4096; local = wvid - 4096; }
        int b = local >> lg, o = local & ((1 << lg) - 1);
        const float* sb = style + b * 512;
        const float* fwo = fw + (size_t)o * 512;
        float p = 0.f;
        #pragma unroll
        for (int k = lane; k < 512; k += 64) p += sb[k] * fwo[k];
        #pragma unroll
        for (int off = 32; off > 0; off >>= 1) p += __shfl_down(p, off);
        if (lane == 0) S[sOff + local] = p + fb[o];
    }
}

// ---------------- stages 1-3: K-full parity-decomposed conv ----------------
template <int HS, int CI, int CO, int NT>
__launch_bounds__(256)
__global__ void conv_sfull_kernel(const __hip_bfloat16* __restrict__ actIn,
                                  const __hip_bfloat16* __restrict__ wpk,
                                  const float* __restrict__ S,
                                  __hip_bfloat16* __restrict__ actOut) {
    constexpr int WS = HS, HO = HS * 2;
    constexpr int CICH = CI / 64, CO16 = CO / 16;
    constexpr int PW = HO / 8, PPI = PW * PW;

    const int tid = threadIdx.x;
    const int lane = tid & 63, wv = tid >> 6;        // wv = parity class
    const int r = lane & 15, q = lane >> 4;
    const int rr2 = r >> 2, cc2 = r & 3;
    const int lane8 = lane * 8;
    const int py = wv >> 1, px = wv & 1;

    const int b = blockIdx.x / PPI;
    const int prest = blockIdx.x - b * PPI;
    const int ph = prest / PW, pwi = prest - ph * PW;
    const int oh0 = ph * 8, ow0 = pwi * 8;
    const int sh0 = oh0 >> 1, sw0 = ow0 >> 1;
    const int co16base = blockIdx.y * NT;
    const int n0 = co16base * 16;

    __shared__ alignas(16) __hip_bfloat16 Tile[36 * 72];   // 6x6 px x 64 ci

    f32x4 acc[NT];
    #pragma unroll
    for (int j = 0; j < NT; ++j) acc[j] = f32x4{0.f, 0.f, 0.f, 0.f};

    bf16x8 bA[NT][2], bB[NT][2];

    #pragma unroll 1
    for (int cich = 0; cich < CICH; ++cich) {
        if (cich) __syncthreads();                   // all waves done with previous Tile
        for (int i = tid; i < 288; i += 256) {
            int pix = i >> 3, koct = i & 7;
            int tr = pix / 6, tc2 = pix - tr * 6;
            int su = sh0 - 1 + tr, sv = sw0 - 1 + tc2;
            uint4 v = {0, 0, 0, 0};
            if (su >= 0 && su < HS && sv >= 0 && sv < WS)
                v = *(const uint4*)(actIn +
                    ((size_t)((b * HS + su) * WS + sv) * CI + cich * 64 + koct * 8));
            *(uint4*)&Tile[pix * 72 + koct * 8] = v;
        }
        __syncthreads();

        auto loadB = [&](bf16x8 (&dst)[NT][2], int tp) {
            #pragma unroll
            for (int nt = 0; nt < NT; ++nt)
                #pragma unroll
                for (int ch = 0; ch < 2; ++ch)
                    dst[nt][ch] = *(const bf16x8*)(wpk +
                        ((size_t)((((wv * 4 + tp) * CO16 + co16base + nt) * CICH + cich) * 2 + ch) << 9) + lane8);
        };

        auto compute = [&](int tp, bf16x8 (&bfr)[NT][2]) {
            const int i = tp >> 1, j = tp & 1;
            const int apix = (rr2 + i + py) * 6 + (cc2 + j + px);
            #pragma unroll
            for (int ch = 0; ch < 2; ++ch) {
                bf16x8 af = *(const bf16x8*)&Tile[apix * 72 + ch * 32 + q * 8];
                #pragma unroll
                for (int nt = 0; nt < NT; ++nt)
                    acc[nt] = __builtin_amdgcn_mfma_f32_16x16x32_bf16(
                        af, bfr[nt][ch], acc[nt], 0, 0, 0);
            }
        };

        loadB(bA, 0);
        loadB(bB, 1);
        compute(0, bA);
        loadB(bA, 2);
        compute(1, bB);
        loadB(bB, 3);
        compute(2, bA);
        compute(3, bB);
    }

    float sv_[NT];
    #pragma unroll
    for (int nt = 0; nt < NT; ++nt) sv_[nt] = S[b * CO + n0 + nt * 16 + r];
    #pragma unroll
    for (int t2 = 0; t2 < 4; ++t2) {
        const int m = q * 4 + t2;
        const int row = oh0 + 2 * (m >> 2) + py;
        const int col = ow0 + 2 * (m & 3) + px;
        const size_t obase = ((size_t)(b * HO + row) * HO + col) * CO + n0;
        #pragma unroll
        for (int nt = 0; nt < NT; ++nt)
            actOut[obase + nt * 16 + r] =
                __float2bfloat16(fmaxf(acc[nt][t2] * sv_[nt], 0.f));
    }
}

// ---------------- stage 4: parity-decomposed 2x2 taps, CO-split (blockIdx.y) ---------
template <int HS, int WS>
__launch_bounds__(256)
__global__ void conv_patch_kernel(const __hip_bfloat16* __restrict__ actIn,
                                  const __hip_bfloat16* __restrict__ wpk,
                                  const float* __restrict__ S,
                                  __hip_bfloat16* __restrict__ actOut) {
    constexpr int HO = HS * 2, WO = WS * 2;

    const int tid = threadIdx.x;
    const int lane = tid & 63, wv = tid >> 6;        // wv = parity class
    const int r = lane & 15, q = lane >> 4;
    const int rs = r >> 3, sc = r & 7;
    const int lane8 = lane * 8;
    const int py = wv >> 1, px = wv & 1;

    const int pw = WO / 16, ppb = (HO / 16) * pw;
    const int b = blockIdx.x / ppb;
    const int prest = blockIdx.x - b * ppb;
    const int ph = prest / pw, pwi = prest - ph * pw;
    const int oh0 = ph * 16, ow0 = pwi * 16;
    const int sh0 = oh0 >> 1, sw0 = ow0 >> 1;
    const int ntBase = blockIdx.y * 2;               // co half: 2 of 4 co16-groups

    __shared__ alignas(16) __hip_bfloat16 Tile[100 * 72];

    f32x4 acc[4][2];
    #pragma unroll
    for (int i = 0; i < 4; ++i)
        #pragma unroll
        for (int j = 0; j < 2; ++j) acc[i][j] = f32x4{0.f, 0.f, 0.f, 0.f};

    for (int i = tid; i < 800; i += 256) {
        int pix = i >> 3, koct = i & 7;
        int tr = pix / 10, tc2 = pix - tr * 10;
        int su = sh0 - 1 + tr, sv = sw0 - 1 + tc2;
        uint4 v = {0, 0, 0, 0};
        if (su >= 0 && su < HS && sv >= 0 && sv < WS)
            v = *(const uint4*)(actIn + ((size_t)((b * HS + su) * WS + sv) * 64 + koct * 8));
        *(uint4*)&Tile[pix * 72 + koct * 8] = v;
    }
    __syncthreads();

    const __hip_bfloat16* wcls = wpk + ((size_t)wv << 14);

    bf16x8 bA[2][2], bB[2][2];

    auto loadB = [&](bf16x8 (&dst)[2][2], int tp) {
        #pragma unroll
        for (int nt = 0; nt < 2; ++nt)
            #pragma unroll
            for (int ch = 0; ch < 2; ++ch)
                dst[nt][ch] = *(const bf16x8*)(wcls + (tp << 12) + (((ntBase + nt) * 2 + ch) << 9) + lane8);
    };

    auto compute = [&](int tp, bf16x8 (&bfr)[2][2]) {
        const int i = tp >> 1, j = tp & 1;
        const int ro = i + py, co2 = j + px;
        int apix[4];
        #pragma unroll
        for (int mt = 0; mt < 4; ++mt)
            apix[mt] = (2 * mt + rs + ro) * 10 + (sc + co2);
        #pragma unroll
        for (int ch = 0; ch < 2; ++ch) {
            bf16x8 af[4];
            #pragma unroll
            for (int mt = 0; mt < 4; ++mt)
                af[mt] = *(const bf16x8*)&Tile[apix[mt] * 72 + ch * 32 + q * 8];
            #pragma unroll
            for (int mt = 0; mt < 4; ++mt)
                #pragma unroll
                for (int nt = 0; nt < 2; ++nt)
                    acc[mt][nt] = __builtin_amdgcn_mfma_f32_16x16x32_bf16(
                        af[mt], bfr[nt][ch], acc[mt][nt], 0, 0, 0);
        }
    };

    loadB(bA, 0);
    loadB(bB, 1);
    compute(0, bA);
    loadB(bA, 2);
    compute(1, bB);
    loadB(bB, 3);
    compute(2, bA);
    compute(3, bB);

    float sv_[2];
    #pragma unroll
    for (int nt = 0; nt < 2; ++nt) sv_[nt] = S[b * 64 + (ntBase + nt) * 16 + r];
    #pragma unroll
    for (int mt = 0; mt < 4; ++mt) {
        #pragma unroll
        for (int t2 = 0; t2 < 4; ++t2) {
            const int m = q * 4 + t2;
            const int row = oh0 + 4 * mt + 2 * (m >> 3) + py;
            const int col = ow0 + 2 * (m & 7) + px;
            const size_t obase = ((size_t)(b * HO + row) * WO + col) * 64;
            #pragma unroll
            for (int nt = 0; nt < 2; ++nt)
                actOut[obase + (ntBase + nt) * 16 + r] =
                    __float2bfloat16(fmaxf(acc[mt][nt][t2] * sv_[nt], 0.f));
        }
    }
}

// ---------------- fused stage 5 + final conv (R13/R17 version — best measured) -------
__launch_bounds__(512)
__global__ void conv_s5f_kernel(const __hip_bfloat16* __restrict__ actIn,  // [8][128][128][64]
                                const __hip_bfloat16* __restrict__ wpk5,   // wt5 parity-packed
                                const __hip_bfloat16* __restrict__ wpkF,   // [9][2][64][8]
                                const float* __restrict__ S,
                                const float* __restrict__ bias,
                                float* __restrict__ out) {                 // [8][3][256][256]
    constexpr int HS = 128, WS = 128;

    const int tid = threadIdx.x;
    const int lane = tid & 63, wv = tid >> 6;        // 8 waves
    const int r = lane & 15, q = lane >> 4;
    const int lane8 = lane * 8;
    const int cls = wv >> 1, half = wv & 1;
    const int py = cls >> 1, px = cls & 1;

    const int bid = blockIdx.x;                      // 8 * 16 * 16 = 2048
    const int b = bid >> 8;
    const int rest = bid & 255;
    const int oh0 = (rest >> 4) * 16, ow0 = (rest & 15) * 16;   // final tile origin
    const int sh0 = oh0 >> 1, sw0 = ow0 >> 1;

    __shared__ alignas(16) __hip_bfloat16 Lds[18 * 18 * 72];    // act5 patch; act4 aliased
    __hip_bfloat16* TileA = Lds;                                // first 100*72 elems

    // ---- stage act4 tile (10x10 x 64ci, stride 72) ----
    for (int i = tid; i < 800; i += 512) {
        int pix = i >> 3, koct = i & 7;
        int tr = pix / 10, tc2 = pix - tr * 10;
        int su = sh0 - 1 + tr, sv = sw0 - 1 + tc2;
        uint4 v = {0, 0, 0, 0};
        if (su >= 0 && su < HS && sv >= 0 && sv < WS)
            v = *(const uint4*)(actIn + ((size_t)((b * HS + su) * WS + sv) * 64 + koct * 8));
        *(uint4*)&TileA[pix * 72 + koct * 8] = v;
    }
    __syncthreads();

    // ---- stage-5 compute: per class 9x9 px grid, this wave-half owns m in [half*48, half*48+48) ----
    f32x4 acc[3][4];                                 // [mt][nt]
    #pragma unroll
    for (int i = 0; i < 3; ++i)
        #pragma unroll
        for (int j = 0; j < 4; ++j) acc[i][j] = f32x4{0.f, 0.f, 0.f, 0.f};

    int jrA[3], jcA[3];                              // A-row px coords (clamped)
    #pragma unroll
    for (int mt = 0; mt < 3; ++mt) {
        int pm = half * 48 + mt * 16 + r;
        pm = pm > 80 ? 80 : pm;
        jrA[mt] = (pm * 57) >> 9;                    // pm / 9 (exact for pm<=95)
        jcA[mt] = pm - jrA[mt] * 9;
    }

    const __hip_bfloat16* wcls = wpk5 + ((size_t)cls << 14);

    bf16x8 bA[4][2], bB[4][2];                       // [nt][ch]

    auto loadB = [&](bf16x8 (&dst)[4][2], int tp) {
        #pragma unroll
        for (int nt = 0; nt < 4; ++nt)
            #pragma unroll
            for (int ch = 0; ch < 2; ++ch)
                dst[nt][ch] = *(const bf16x8*)(wcls + (tp << 12) + ((nt * 2 + ch) << 9) + lane8);
    };

    auto compute = [&](int tp, bf16x8 (&bfr)[4][2]) {
        const int i = tp >> 1, j = tp & 1;
        int apix[3];
        #pragma unroll
        for (int mt = 0; mt < 3; ++mt)
            apix[mt] = (jrA[mt] + i) * 10 + (jcA[mt] + j);
        #pragma unroll
        for (int ch = 0; ch < 2; ++ch) {
            bf16x8 af[3];
            #pragma unroll
            for (int mt = 0; mt < 3; ++mt)
                af[mt] = *(const bf16x8*)&TileA[apix[mt] * 72 + ch * 32 + q * 8];
            #pragma unroll
            for (int mt = 0; mt < 3; ++mt)
                #pragma unroll
                for (int nt = 0; nt < 4; ++nt)
                    acc[mt][nt] = __builtin_amdgcn_mfma_f32_16x16x32_bf16(
                        af[mt], bfr[nt][ch], acc[mt][nt], 0, 0, 0);
        }
    };

    loadB(bA, 0);
    loadB(bB, 1);
    compute(0, bA);
    loadB(bA, 2);
    compute(1, bB);
    loadB(bB, 3);
    compute(2, bA);
    compute(3, bB);

    float sv_[4];
    #pragma unroll
    for (int nt = 0; nt < 4; ++nt) sv_[nt] = S[b * 64 + nt * 16 + r];

    __syncthreads();                                 // all TileA reads done

    // ---- write act5 patch to LDS (classes exactly partition the 18x18 grid;
    //      out-of-image px written as 0 = conv zero-padding) ----
    #pragma unroll
    for (int mt = 0; mt < 3; ++mt) {
        #pragma unroll
        for (int t2 = 0; t2 < 4; ++t2) {
            const int m = half * 48 + mt * 16 + q * 4 + t2;
            if (m < 81) {
                const int jr = (m * 57) >> 9;
                const int jc = m - jr * 9;
                const int p  = py ? (oh0 - 1 + 2 * jr) : (oh0 + 2 * jr);
                const int pc = px ? (ow0 - 1 + 2 * jc) : (ow0 + 2 * jc);
                const bool valid = (p >= 0) && (p < 256) && (pc >= 0) && (pc < 256);
                const int dpx = (2 * jr + 1 - py) * 18 + (2 * jc + 1 - px);
                #pragma unroll
                for (int nt = 0; nt < 4; ++nt) {
                    float v = valid ? fmaxf(acc[mt][nt][t2] * sv_[nt], 0.f) : 0.f;
                    Lds[dpx * 72 + nt * 16 + r] = __float2bfloat16(v);
                }
            }
        }
    }
    __syncthreads();

    // ---- final conv from LDS: 8 waves x 2 rows x 16 cols ----
    f32x4 acc2[2];
    acc2[0] = f32x4{0.f, 0.f, 0.f, 0.f};
    acc2[1] = f32x4{0.f, 0.f, 0.f, 0.f};

    #pragma unroll 1
    for (int tap = 0; tap < 9; ++tap) {
        const int dyv = tap / 3;
        const int dxv = tap - dyv * 3;
        const int tc = r + dxv;
        int apix[2];
        #pragma unroll
        for (int mt = 0; mt < 2; ++mt)
            apix[mt] = (wv * 2 + mt + dyv) * 18 + tc;
        #pragma unroll
        for (int ch = 0; ch < 2; ++ch) {
            bf16x8 bfr = *(const bf16x8*)(wpkF + ((tap * 2 + ch) << 9) + lane8);
            #pragma unroll
            for (int mt = 0; mt < 2; ++mt) {
                bf16x8 af = *(const bf16x8*)&Lds[apix[mt] * 72 + ch * 32 + q * 8];
                acc2[mt] = __builtin_amdgcn_mfma_f32_16x16x32_bf16(af, bfr, acc2[mt], 0, 0, 0);
            }
        }
    }

    if (r < 3) {
        const float bs = bias[r];
        #pragma unroll
        for (int mt = 0; mt < 2; ++mt) {
            const int prow = oh0 + wv * 2 + mt;
            #pragma unroll
            for (int t2 = 0; t2 < 4; ++t2)
                out[((size_t)(b * 3 + r) << 16) + prow * 256 + ow0 + q * 4 + t2] =
                    acc2[mt][t2] + bs;
        }
    }
}

// ---------------- launch ----------------
extern "C" void kernel_launch(void* const* d_in, const int* in_sizes, int n_in,
                              void* d_out, int out_size, void* d_ws, size_t ws_size,
                              hipStream_t stream) {
    const float* x    = (const float*)d_in[0];
    const float* sty  = (const float*)d_in[1];
    const float* w1   = (const float*)d_in[2];
    const float* fw1  = (const float*)d_in[3];
    const float* fb1  = (const float*)d_in[4];
    const float* w2   = (const float*)d_in[5];
    const float* fw2  = (const float*)d_in[6];
    const float* fb2  = (const float*)d_in[7];
    const float* w3   = (const float*)d_in[8];
    const float* fw3  = (const float*)d_in[9];
    const float* fb3  = (const float*)d_in[10];
    const float* w4   = (const float*)d_in[11];
    const float* fw4  = (const float*)d_in[12];
    const float* fb4  = (const float*)d_in[13];
    const float* w5   = (const float*)d_in[14];
    const float* fw5  = (const float*)d_in[15];
    const float* fb5  = (const float*)d_in[16];
    const float* wf   = (const float*)d_in[17];
    const float* bf   = (const float*)d_in[18];
    float* out = (float*)d_out;

    char* ws = (char*)d_ws;
    size_t off = 0;
    auto alloc = [&](size_t bytes) {
        char* p = ws + off;
        off += (bytes + 255) & ~(size_t)255;
        return p;
    };
    float* S1 = (float*)alloc(8 * 256 * 4);
    float* S2 = (float*)alloc(8 * 128 * 4);
    float* S3 = (float*)alloc(8 * 64 * 4);
    float* S4 = (float*)alloc(8 * 64 * 4);
    float* S5 = (float*)alloc(8 * 64 * 4);
    __hip_bfloat16* act0 = (__hip_bfloat16*)alloc((size_t)262144 * 2);   // 8x8x8x512
    __hip_bfloat16* act1 = (__hip_bfloat16*)alloc((size_t)524288 * 2);   // 8x16x16x256
    __hip_bfloat16* act2 = (__hip_bfloat16*)alloc((size_t)1048576 * 2);  // 8x32x32x128
    __hip_bfloat16* act3 = (__hip_bfloat16*)alloc((size_t)2097152 * 2);  // 8x64x64x64
    __hip_bfloat16* act4 = (__hip_bfloat16*)alloc((size_t)8388608 * 2);  // 8x128x128x64
    __hip_bfloat16* wt1  = (__hip_bfloat16*)alloc((size_t)2097152 * 2);  // parity-packed
    __hip_bfloat16* wt2  = (__hip_bfloat16*)alloc((size_t)524288 * 2);   // parity-packed
    __hip_bfloat16* wt3  = (__hip_bfloat16*)alloc((size_t)131072 * 2);   // parity-packed
    __hip_bfloat16* wt4  = (__hip_bfloat16*)alloc((size_t)65536 * 2);    // parity-packed
    __hip_bfloat16* wt5  = (__hip_bfloat16*)alloc((size_t)65536 * 2);    // parity-packed
    __hip_bfloat16* wtF  = (__hip_bfloat16*)alloc((size_t)9 * 16 * 64 * 2); // packed 16x16
    if (off > ws_size) return;

    // fused prep: convert_x [0,1024) | weights [1024,12324) | style [12324,13476)
    prep_all_kernel<<<13476, 256, 0, stream>>>(x, act0,
                                               w1, wt1, w2, wt2, w3, wt3,
                                               w4, wt4, w5, wt5, wf, wtF,
                                               sty, fw1, fb1, fw2, fb2, fw3, fb3,
                                               fw4, fb4, fw5, fb5, S1);

    // stages 1-3: K-full parity-decomposed; s2/s3 CO-split for 2x block count
    conv_sfull_kernel<8, 512, 256, 1><<<dim3(32, 16), 256, 0, stream>>>(act0, wt1, S1, act1);
    conv_sfull_kernel<16, 256, 128, 1><<<dim3(128, 8), 256, 0, stream>>>(act1, wt2, S2, act2);
    conv_sfull_kernel<32, 128, 64, 2><<<dim3(512, 2), 256, 0, stream>>>(act2, wt3, S3, act3);

    // stage 4: parity-decomposed 2x2-tap fused conv, CO-split (1024 blocks)
    conv_patch_kernel<64, 64><<<dim3(512, 2), 256, 0, stream>>>(act3, wt4, S4, act4);

    // stage 5 + final conv fused (act5 lives only in LDS)
    conv_s5f_kernel<<<2048, 512, 0, stream>>>(act4, wt5, wtF, S5, bf, out);
}